// Round 4
// baseline (1480.560 us; speedup 1.0000x reference)
//
#include <hip/hip_runtime.h>
#include <hip/hip_bf16.h>

// Problem dims (fixed by setup_inputs)
#define M_DIM 8192     // B*S = 4*2048
#define N_DIM 11008    // OUT
#define K_DIM 4096     // IN
#define BM 128
#define BN 128
#define BK 32
#define NT (K_DIM / BK)        // 128 K-tiles
#define TM (M_DIM / BM)        // 64
#define TN (N_DIM / BN)        // 86
#define NBLK (TM * TN)         // 5504 (divisible by 8 -> bijective XCD swizzle)

typedef __attribute__((ext_vector_type(8))) short short8;
typedef __attribute__((ext_vector_type(4))) float floatx4;

static_assert(M_DIM % BM == 0 && N_DIM % BN == 0 && K_DIM % BK == 0, "tiling");

// round-to-nearest-even fp32 -> bf16 bits
__device__ __forceinline__ unsigned short f2bf(float f) {
  unsigned u = __builtin_bit_cast(unsigned, f);
  u += 0x7FFFu + ((u >> 16) & 1u);
  return (unsigned short)(u >> 16);
}

__device__ __forceinline__ void gload_lds16(const void* g, void* l) {
  __builtin_amdgcn_global_load_lds((const __attribute__((address_space(1))) void*)g,
                                   (__attribute__((address_space(3))) void*)l, 16, 0, 0);
}

// ---------------------------------------------------------------------------
// Kernel 1: dequant qweight -> Wt bf16, TRANSPOSED to [N][K].
// 32n x 64k tile per block, transposed through LDS so BOTH the qweight read
// and the Wt write are coalesced. LDS row stride 72 shorts (144B): write and
// read phases each hit every bank exactly 8x per wave (= minimum for 1KB).
// ---------------------------------------------------------------------------
__global__ __launch_bounds__(256) void dequant_wt_kernel(
    const unsigned* __restrict__ qweight, const unsigned* __restrict__ qzeros,
    const float* __restrict__ scales, const int* __restrict__ g_idx,
    unsigned short* __restrict__ wt)
{
  __shared__ unsigned short lt[32 * 72];
  const int tid = threadIdx.x;
  const int n0 = blockIdx.x * 32;    // 344 tiles along N
  const int kk0 = blockIdx.y * 8;    // 64 tiles along K (8 packed int32 rows)
  const int nl = tid & 31, kkl = tid >> 5;           // n-local 0..31, kk-local 0..7
  const int n = n0 + nl, kk = kk0 + kkl;
  const int k0 = kk * 8;

  const unsigned q = qweight[(size_t)kk * N_DIM + n];
  const int g0 = g_idx[k0];
  const int g7 = g_idx[k0 + 7];
  short8 v;
  if (g0 == g7) {   // group uniform across the 8 packed rows (true for i//128)
    const unsigned zw = qzeros[(size_t)g0 * (N_DIM / 8) + (n >> 3)];
    const float z = (float)(((zw >> ((n & 7) * 4)) & 0xFu) + 1u);
    const float s = scales[(size_t)g0 * N_DIM + n];
#pragma unroll
    for (int j = 0; j < 8; ++j)
      v[j] = (short)f2bf(((float)((q >> (4 * j)) & 0xFu) - z) * s);
  } else {          // general g_idx fallback
#pragma unroll
    for (int j = 0; j < 8; ++j) {
      const int g = g_idx[k0 + j];
      const unsigned zw = qzeros[(size_t)g * (N_DIM / 8) + (n >> 3)];
      const float z = (float)(((zw >> ((n & 7) * 4)) & 0xFu) + 1u);
      const float s = scales[(size_t)g * N_DIM + n];
      v[j] = (short)f2bf(((float)((q >> (4 * j)) & 0xFu) - z) * s);
    }
  }
  *(short8*)&lt[nl * 72 + kkl * 8] = v;
  __syncthreads();
  // write out coalesced: 8 lanes cover one n-row's 64 k (128B contiguous)
  const int no = tid >> 3, ko = (tid & 7) * 8;
  const short8 o = *(const short8*)&lt[no * 72 + ko];
  *(short8*)&wt[(size_t)(n0 + no) * K_DIM + blockIdx.y * 64 + ko] = o;
}

// ---------------------------------------------------------------------------
// Kernel 2: cast X fp32 -> bf16 (vectorized 8 elems/thread)
// ---------------------------------------------------------------------------
__global__ __launch_bounds__(256) void cast_x_kernel(
    const float* __restrict__ x, unsigned short* __restrict__ xb)
{
  const int n8 = (M_DIM * K_DIM) / 8;  // 4,194,304
  for (int i = blockIdx.x * 256 + threadIdx.x; i < n8; i += gridDim.x * 256) {
    const float4* src = (const float4*)(x + (size_t)i * 8);
    const float4 a = src[0];
    const float4 b = src[1];
    short8 v;
    v[0] = (short)f2bf(a.x); v[1] = (short)f2bf(a.y);
    v[2] = (short)f2bf(a.z); v[3] = (short)f2bf(a.w);
    v[4] = (short)f2bf(b.x); v[5] = (short)f2bf(b.y);
    v[6] = (short)f2bf(b.z); v[7] = (short)f2bf(b.w);
    *(short8*)(xb + (size_t)i * 8) = v;
  }
}

// ---------------------------------------------------------------------------
// Kernel 3 (fast path): 128x128 tile bf16 GEMM, BK=32, 4 waves (2x2),
// global_load_lds staging with pre-swizzled source (chunk XOR (row>>1)&3),
// double-buffered LDS, 16x16x32 bf16 MFMA, bias fused.
//   Xb: [M][K] bf16 bits, Wt: [N][K] bf16 bits, out: [M][N] fp32
// ---------------------------------------------------------------------------
__global__ __launch_bounds__(256, 3) void gemm_bf16_kernel(
    const unsigned short* __restrict__ Xb, const unsigned short* __restrict__ Wt,
    const float* __restrict__ bias, float* __restrict__ out)
{
  __shared__ unsigned short As[2][BM * BK];  // 8 KB each buf
  __shared__ unsigned short Bs[2][BN * BK];

  const int tid = threadIdx.x;
  const int lane = tid & 63;
  const int w = tid >> 6;           // wave 0..3
  const int wr = w >> 1, wc = w & 1;

  // XCD-aware bijective swizzle (NBLK % 8 == 0)
  const int bid = blockIdx.x;
  const int wg = (bid & 7) * (NBLK / 8) + (bid >> 3);
  const int tm = wg / TN, tn = wg % TN;
  const int blockM = tm * BM, blockN = tn * BN;

  const int srow = lane >> 2;       // staging row within 16-row group
  const int scl = lane & 3;         // staging physical 16B chunk

  auto stage = [&](int b, int t) {
#pragma unroll
    for (int i = 0; i < 2; ++i) {
      const int row = i * 64 + w * 16 + srow;           // 0..127
      const int cs = scl ^ ((row >> 1) & 3);            // pre-swizzled src chunk
      gload_lds16(Xb + (size_t)(blockM + row) * K_DIM + t * BK + cs * 8,
                  &As[b][(i * 64 + w * 16) * BK]);
      gload_lds16(Wt + (size_t)(blockN + row) * K_DIM + t * BK + cs * 8,
                  &Bs[b][(i * 64 + w * 16) * BK]);
    }
  };

  floatx4 acc[4][4] = {};
  stage(0, 0);
  __syncthreads();
  int buf = 0;
  for (int t = 0; t < NT; ++t) {
    if (t + 1 < NT) stage(buf ^ 1, t + 1);
    const int klog = lane >> 4;                         // logical k-chunk 0..3
    short8 af[4], bfr[4];
#pragma unroll
    for (int mi = 0; mi < 4; ++mi) {
      const int row = wr * 64 + mi * 16 + (lane & 15);
      const int pc = klog ^ ((row >> 1) & 3);
      af[mi] = *(const short8*)&As[buf][row * BK + pc * 8];
    }
#pragma unroll
    for (int ni = 0; ni < 4; ++ni) {
      const int row = wc * 64 + ni * 16 + (lane & 15);
      const int pc = klog ^ ((row >> 1) & 3);
      bfr[ni] = *(const short8*)&Bs[buf][row * BK + pc * 8];
    }
#pragma unroll
    for (int mi = 0; mi < 4; ++mi)
#pragma unroll
      for (int ni = 0; ni < 4; ++ni)
        acc[mi][ni] = __builtin_amdgcn_mfma_f32_16x16x32_bf16(
            af[mi], bfr[ni], acc[mi][ni], 0, 0, 0);
    __syncthreads();
    buf ^= 1;
  }

  // epilogue: C/D layout col = lane&15, row = (lane>>4)*4 + reg
#pragma unroll
  for (int ni = 0; ni < 4; ++ni) {
    const int n = blockN + wc * 64 + ni * 16 + (lane & 15);
    const float bv = bias[n];
#pragma unroll
    for (int mi = 0; mi < 4; ++mi) {
      const size_t m = (size_t)blockM + wr * 64 + mi * 16 + (lane >> 4) * 4;
      float* o = out + m * N_DIM + n;
#pragma unroll
      for (int r = 0; r < 4; ++r)
        o[(size_t)r * N_DIM] = acc[mi][ni][r] + bv;
    }
  }
}

// ---------------------------------------------------------------------------
// Fallback (small ws): fully fused — reg-stage X (fp32->bf16) and dequant
// qweight inline during LDS staging. Same GEMM core.
// ---------------------------------------------------------------------------
__global__ __launch_bounds__(256, 2) void gemm_fused_kernel(
    const float* __restrict__ X, const unsigned* __restrict__ qweight,
    const unsigned* __restrict__ qzeros, const float* __restrict__ scales,
    const int* __restrict__ g_idx, const float* __restrict__ bias,
    float* __restrict__ out)
{
  __shared__ unsigned short As[2][BM * BK];
  __shared__ unsigned short Bs[2][BN * BK];

  const int tid = threadIdx.x;
  const int lane = tid & 63;
  const int w = tid >> 6;
  const int wr = w >> 1, wc = w & 1;

  const int bid = blockIdx.x;
  const int wg = (bid & 7) * (NBLK / 8) + (bid >> 3);
  const int tm = wg / TN, tn = wg % TN;
  const int blockM = tm * BM, blockN = tn * BN;

  const int srow = lane >> 2;
  const int scl = lane & 3;

  auto stageF = [&](int b, int t) {
#pragma unroll
    for (int i = 0; i < 2; ++i) {
      const int row = i * 64 + w * 16 + srow;
      const int pc = scl ^ ((row >> 1) & 3);   // physical chunk for logical scl
      {
        const float* src = X + (size_t)(blockM + row) * K_DIM + t * BK + scl * 8;
        const float4 f0 = *(const float4*)src;
        const float4 f1 = *(const float4*)(src + 4);
        short8 v;
        v[0] = (short)f2bf(f0.x); v[1] = (short)f2bf(f0.y);
        v[2] = (short)f2bf(f0.z); v[3] = (short)f2bf(f0.w);
        v[4] = (short)f2bf(f1.x); v[5] = (short)f2bf(f1.y);
        v[6] = (short)f2bf(f1.z); v[7] = (short)f2bf(f1.w);
        *(short8*)&As[b][row * BK + pc * 8] = v;
      }
      {
        const int n = blockN + row;
        const int kk = t * (BK / 8) + scl;    // packed row index, k = kk*8
        const unsigned q = qweight[(size_t)kk * N_DIM + n];
        const int g = g_idx[kk * 8];
        const unsigned zw = qzeros[(size_t)g * (N_DIM / 8) + (n >> 3)];
        const float z = (float)(((zw >> ((n & 7) * 4)) & 0xFu) + 1u);
        const float s = scales[(size_t)g * N_DIM + n];
        short8 v;
#pragma unroll
        for (int j = 0; j < 8; ++j)
          v[j] = (short)f2bf(((float)((q >> (4 * j)) & 0xFu) - z) * s);
        *(short8*)&Bs[b][row * BK + pc * 8] = v;
      }
    }
  };

  floatx4 acc[4][4] = {};
  stageF(0, 0);
  __syncthreads();
  int buf = 0;
  for (int t = 0; t < NT; ++t) {
    if (t + 1 < NT) stageF(buf ^ 1, t + 1);
    const int klog = lane >> 4;
    short8 af[4], bfr[4];
#pragma unroll
    for (int mi = 0; mi < 4; ++mi) {
      const int row = wr * 64 + mi * 16 + (lane & 15);
      const int pc = klog ^ ((row >> 1) & 3);
      af[mi] = *(const short8*)&As[buf][row * BK + pc * 8];
    }
#pragma unroll
    for (int ni = 0; ni < 4; ++ni) {
      const int row = wc * 64 + ni * 16 + (lane & 15);
      const int pc = klog ^ ((row >> 1) & 3);
      bfr[ni] = *(const short8*)&Bs[buf][row * BK + pc * 8];
    }
#pragma unroll
    for (int mi = 0; mi < 4; ++mi)
#pragma unroll
      for (int ni = 0; ni < 4; ++ni)
        acc[mi][ni] = __builtin_amdgcn_mfma_f32_16x16x32_bf16(
            af[mi], bfr[ni], acc[mi][ni], 0, 0, 0);
    __syncthreads();
    buf ^= 1;
  }

#pragma unroll
  for (int ni = 0; ni < 4; ++ni) {
    const int n = blockN + wc * 64 + ni * 16 + (lane & 15);
    const float bv = bias[n];
#pragma unroll
    for (int mi = 0; mi < 4; ++mi) {
      const size_t m = (size_t)blockM + wr * 64 + mi * 16 + (lane >> 4) * 4;
      float* o = out + m * N_DIM + n;
#pragma unroll
      for (int r = 0; r < 4; ++r)
        o[(size_t)r * N_DIM] = acc[mi][ni][r] + bv;
    }
  }
}

// ---------------------------------------------------------------------------
extern "C" void kernel_launch(void* const* d_in, const int* in_sizes, int n_in,
                              void* d_out, int out_size, void* d_ws, size_t ws_size,
                              hipStream_t stream) {
  const float* x = (const float*)d_in[0];
  const unsigned* qweight = (const unsigned*)d_in[1];
  const unsigned* qzeros = (const unsigned*)d_in[2];
  const float* scales = (const float*)d_in[3];
  const int* g_idx = (const int*)d_in[4];
  const float* bias = (const float*)d_in[5];
  float* out = (float*)d_out;

  const size_t wt_bytes = (size_t)N_DIM * K_DIM * 2;  // 90,177,536
  const size_t xb_bytes = (size_t)M_DIM * K_DIM * 2;  // 67,108,864

  if (ws_size >= wt_bytes + xb_bytes && d_ws != nullptr) {
    unsigned short* wt = (unsigned short*)d_ws;
    unsigned short* xb = (unsigned short*)((char*)d_ws + wt_bytes);
    dequant_wt_kernel<<<dim3(N_DIM / 32, K_DIM / 64), 256, 0, stream>>>(
        qweight, qzeros, scales, g_idx, wt);
    cast_x_kernel<<<2048, 256, 0, stream>>>(x, xb);
    gemm_bf16_kernel<<<NBLK, 256, 0, stream>>>(xb, wt, bias, out);
  } else {
    gemm_fused_kernel<<<NBLK, 256, 0, stream>>>(
        x, qweight, qzeros, scales, g_idx, bias, out);
  }
}